// Round 3
// baseline (260.970 us; speedup 1.0000x reference)
//
#include <hip/hip_runtime.h>
#include <hip/hip_bf16.h>

// Problem: B=256, T=256, C=384, H=64, MAX_REL=3 (causal -> rel idx 0..3 only)
// Round 3: un-fused, occupancy-first design.
//   prep_wt: weight transpose->bf16 (tiny)
//   qkv_kernel: no-LDS, no-barrier projection; weights via L1/L2; 12 waves/CU
//   attn_kernel: round-1 verified attention (LDS P round-trip, band-prob w2)

typedef __attribute__((ext_vector_type(8))) __bf16 bf16x8;
typedef __attribute__((ext_vector_type(8))) short short8;
typedef __attribute__((ext_vector_type(4))) float f32x4;
typedef __attribute__((ext_vector_type(4))) int   i32x4;

#define MFMA16(A, B, C) __builtin_amdgcn_mfma_f32_16x16x32_bf16((A), (B), (C), 0, 0, 0)

__device__ __forceinline__ unsigned short f2bf(float f) {
    unsigned int u = __builtin_bit_cast(unsigned int, f);
    u = (u + 0x7FFFu + ((u >> 16) & 1u)) >> 16;   // RNE
    return (unsigned short)u;
}
__device__ __forceinline__ float bf2f(unsigned short s) {
    unsigned int u = ((unsigned int)s) << 16;
    return __builtin_bit_cast(float, u);
}
__device__ __forceinline__ bf16x8 ld16(const unsigned short* p) {
    return __builtin_bit_cast(bf16x8, *(const i32x4*)p);
}

// ---------------------------------------------------------------------------
// Kernel 0: Wt[3][64][384] bf16 = transpose+convert of Wq/Wk/Wv [384][64] f32
// ---------------------------------------------------------------------------
__global__ void prep_wt(const float* __restrict__ Wq, const float* __restrict__ Wk,
                        const float* __restrict__ Wv, unsigned short* __restrict__ Wt) {
    int i = blockIdx.x * 256 + threadIdx.x;           // 3*64*384 = 73728
    if (i >= 3 * 64 * 384) return;
    int kk = i % 384;
    int h  = (i / 384) & 63;
    int w  = i / (384 * 64);
    const float* W = (w == 0) ? Wq : ((w == 1) ? Wk : Wv);
    Wt[i] = f2bf(W[kk * 64 + h]);
}

// ---------------------------------------------------------------------------
// Kernel 1: QKV projection, occupancy-first.
//   Grid 1024 x 256 thr (4 waves). Wave w owns m-tile rows [bx*64+16w, +16).
//   No LDS, no barriers. Weight frags straight from global: all 4 waves load
//   identical addresses per k-step -> L1 dedups, L2-resident (147 KB total).
//   x read once as f32 (RNE->bf16 in reg). v produced TRANSPOSED (vT[b][h][t])
//   by swapping MFMA operands (A = Wv^T rows, B = x rows; x B-frag == A-frag).
//   Acc budget: 12 f32x4 = 48 VGPR -> fits 3 waves/SIMD cap (170).
// ---------------------------------------------------------------------------
__global__ __launch_bounds__(256, 3) void qkv_kernel(
        const float* __restrict__ x, const unsigned short* __restrict__ Wt,
        unsigned short* __restrict__ q, unsigned short* __restrict__ k,
        unsigned short* __restrict__ vT) {
    const int tid  = threadIdx.x;
    const int wave = tid >> 6;
    const int lane = tid & 63;
    const int c    = lane & 15;
    const int quad = lane >> 4;
    const int row0 = blockIdx.x * 64 + wave * 16;      // wave's m-tile base row

    f32x4 zero = {0.f, 0.f, 0.f, 0.f};
    f32x4 aq[4], ak[4], av[4];
#pragma unroll
    for (int i = 0; i < 4; i++) { aq[i] = zero; ak[i] = zero; av[i] = zero; }

    const float* xp0 = x + (size_t)(row0 + c) * 384;

#pragma unroll 2
    for (int kc = 0; kc < 12; kc++) {
        const int ko = kc * 32 + quad * 8;
        // x A-frag (also used as B-frag for vT)
        f32x4 x0 = *(const f32x4*)(xp0 + ko);
        f32x4 x1 = *(const f32x4*)(xp0 + ko + 4);
        short8 xs;
#pragma unroll
        for (int j = 0; j < 4; j++) { xs[j] = (short)f2bf(x0[j]); xs[4 + j] = (short)f2bf(x1[j]); }
        bf16x8 a = __builtin_bit_cast(bf16x8, xs);

        // weight frags (wave-uniform addresses -> L1 hit for waves 1..3)
        bf16x8 bq[4], bk[4], aw[4];
#pragma unroll
        for (int nt = 0; nt < 4; nt++) {
            bq[nt] = ld16(Wt + (nt * 16 + c) * 384 + ko);          // Wq^T rows
            bk[nt] = ld16(Wt + (64 + nt * 16 + c) * 384 + ko);     // Wk^T rows
            aw[nt] = ld16(Wt + (128 + nt * 16 + c) * 384 + ko);    // Wv^T rows
        }
#pragma unroll
        for (int nt = 0; nt < 4; nt++) {
            aq[nt] = MFMA16(a, bq[nt], aq[nt]);    // D[t][h]
            ak[nt] = MFMA16(a, bk[nt], ak[nt]);    // D[t][h]
            av[nt] = MFMA16(aw[nt], a, av[nt]);    // D[h][t]  (swapped operands)
        }
    }

    // epilogue: C/D layout col=lane&15, row=quad*4+reg
    const int b   = row0 >> 8;
    const int t0b = row0 & 255;
#pragma unroll
    for (int nt = 0; nt < 4; nt++) {
#pragma unroll
        for (int r = 0; r < 4; r++) {
            int row = row0 + quad * 4 + r;
            q[row * 64 + nt * 16 + c] = f2bf(aq[nt][r]);
            k[row * 64 + nt * 16 + c] = f2bf(ak[nt][r]);
            int h = nt * 16 + quad * 4 + r;
            vT[(b * 64 + h) * 256 + t0b + c] = f2bf(av[nt][r]);
        }
    }
}

// ---------------------------------------------------------------------------
// Kernel 2: causal attention with Shaw relative positions (round-1 verified).
//   Grid (4, 256): blockIdx.x = 64-row q-tile, blockIdx.y = batch.
//   Block 256 thr (4 waves). LDS 38 KB -> 4 blocks/CU.
// ---------------------------------------------------------------------------
__global__ __launch_bounds__(256, 3) void attn_kernel(
        const unsigned short* __restrict__ q, const unsigned short* __restrict__ k,
        const unsigned short* __restrict__ vT,
        const float* __restrict__ relk, const float* __restrict__ relv,
        float* __restrict__ out) {
    __shared__ unsigned short P[64][264];              // 33792 B
    __shared__ float E[64][4];

    const int tid  = threadIdx.x;
    const int wave = tid >> 6;
    const int lane = tid & 63;
    const int c    = lane & 15;
    const int quad = lane >> 4;
    const int tt   = blockIdx.x;
    const int b    = blockIdx.y;
    const int t0   = tt * 64;
    const int nst  = 4 * (tt + 1);                     // valid 16-wide s-tiles

    // Phase 0: E[r][j] = q[b][t0+r] . rel_k[j], j = 0..3
    {
        int r = tid >> 2, j = tid & 3;
        const unsigned short* qr = q + (size_t)(b * 256 + t0 + r) * 64;
        const float* rk = relk + j * 64;
        float e = 0.f;
#pragma unroll
        for (int hh = 0; hh < 64; hh += 8) {
            i32x4 d = *(const i32x4*)(qr + hh);
            const unsigned short* u = (const unsigned short*)&d;
#pragma unroll
            for (int j2 = 0; j2 < 8; j2++) e += bf2f(u[j2]) * rk[hh + j2];
        }
        E[r][j] = e;
    }
    __syncthreads();

    // q A-frags for this lane's row (m = lane&15)
    const unsigned short* qp = q + (size_t)(b * 256 + t0 + wave * 16 + c) * 64 + quad * 8;
    bf16x8 aq0 = ld16(qp);
    bf16x8 aq1 = ld16(qp + 32);

    // Phase 1: S = Q K^T over valid s-tiles
    f32x4 s[16];
    f32x4 zero = {0.f, 0.f, 0.f, 0.f};
#pragma unroll
    for (int st = 0; st < 16; st++) s[st] = zero;
#pragma unroll
    for (int st = 0; st < 16; st++) {
        if (st < nst) {
            const unsigned short* kp = k + (size_t)(b * 256 + st * 16 + c) * 64 + quad * 8;
            s[st] = MFMA16(aq0, ld16(kp), s[st]);
            s[st] = MFMA16(aq1, ld16(kp + 32), s[st]);
        }
    }

    // Phase 2: rel-pos add + scale + causal mask; row max
    const int rbase = wave * 16 + quad * 4;            // local row base (0..63)
    f32x4 ef[4];
#pragma unroll
    for (int r = 0; r < 4; r++) ef[r] = *(const f32x4*)(&E[rbase + r][0]);

    float m[4] = {-3.0e38f, -3.0e38f, -3.0e38f, -3.0e38f};
#pragma unroll
    for (int st = 0; st < 16; st++) {
        if (st < nst) {
#pragma unroll
            for (int r = 0; r < 4; r++) {
                int tl = rbase + r;
                int d  = st * 16 + c - (t0 + tl);      // s - t
                float e  = (d <= -3) ? ef[r][0] : (d == -2) ? ef[r][1]
                         : (d == -1) ? ef[r][2] : ef[r][3];
                float sc = (d > 0) ? -1.0e30f : 0.125f * (s[st][r] + e);
                s[st][r] = sc;
                m[r] = fmaxf(m[r], sc);
            }
        }
    }
#pragma unroll
    for (int r = 0; r < 4; r++)
#pragma unroll
        for (int ofs = 1; ofs < 16; ofs <<= 1)
            m[r] = fmaxf(m[r], __shfl_xor(m[r], ofs, 64));

    // Phase 3: exp + row sum + normalize; write P (bf16, wave-private rows)
    float l[4] = {0.f, 0.f, 0.f, 0.f};
#pragma unroll
    for (int st = 0; st < 16; st++) {
        if (st < nst) {
#pragma unroll
            for (int r = 0; r < 4; r++) {
                float p = __expf(s[st][r] - m[r]);
                s[st][r] = p;
                l[r] += p;
            }
        }
    }
#pragma unroll
    for (int r = 0; r < 4; r++)
#pragma unroll
        for (int ofs = 1; ofs < 16; ofs <<= 1)
            l[r] += __shfl_xor(l[r], ofs, 64);
    float rl[4];
#pragma unroll
    for (int r = 0; r < 4; r++) rl[r] = 1.0f / l[r];

#pragma unroll
    for (int st = 0; st < 16; st++) {
        if (st < nst) {
#pragma unroll
            for (int r = 0; r < 4; r++)
                P[rbase + r][st * 16 + c] = f2bf(s[st][r] * rl[r]);
        }
    }
    __syncthreads();

    // Phase 4: O = P @ V  (A = P rows from LDS, B = vT rows from global)
    f32x4 o[4];
#pragma unroll
    for (int nt = 0; nt < 4; nt++) o[nt] = zero;
    const int ksteps = nst >> 1;
#pragma unroll
    for (int ks = 0; ks < 8; ks++) {
        if (ks < ksteps) {
            bf16x8 ap = ld16(&P[wave * 16 + c][ks * 32 + quad * 8]);
#pragma unroll
            for (int nt = 0; nt < 4; nt++) {
                const unsigned short* vp = vT + (size_t)(b * 64 + nt * 16 + c) * 256
                                              + ks * 32 + quad * 8;
                o[nt] = MFMA16(ap, ld16(vp), o[nt]);
            }
        }
    }

    // Phase 5: w2 from band probabilities + store
#pragma unroll
    for (int r = 0; r < 4; r++) {
        int tl = rbase + r;
        int tg = t0 + tl;
        int ia = (tg >= 2) ? tg - 2 : 0;
        int ib = (tg >= 1) ? tg - 1 : 0;
        float pa = (tg >= 2) ? bf2f(P[tl][ia]) : 0.f;
        float pb = (tg >= 1) ? bf2f(P[tl][ib]) : 0.f;
        float pc = bf2f(P[tl][tg]);
#pragma unroll
        for (int nt = 0; nt < 4; nt++) {
            int h = nt * 16 + c;
            float r0 = relv[h], r1 = relv[64 + h], r2 = relv[128 + h], r3 = relv[192 + h];
            float w2 = r0 + pa * (r1 - r0) + pb * (r2 - r0) + pc * (r3 - r0);
            out[(size_t)(b * 256 + tg) * 64 + h] = o[nt][r] + w2;
        }
    }
}

// ---------------------------------------------------------------------------
extern "C" void kernel_launch(void* const* d_in, const int* in_sizes, int n_in,
                              void* d_out, int out_size, void* d_ws, size_t ws_size,
                              hipStream_t stream) {
    const float* x    = (const float*)d_in[0];
    const float* Wq   = (const float*)d_in[1];
    const float* Wk   = (const float*)d_in[2];
    const float* Wv   = (const float*)d_in[3];
    const float* relk = (const float*)d_in[4];
    const float* relv = (const float*)d_in[5];
    float* out = (float*)d_out;

    char* ws = (char*)d_ws;
    unsigned short* q  = (unsigned short*)(ws);                 // 8 MiB
    unsigned short* kk = (unsigned short*)(ws + 8388608);       // 8 MiB
    unsigned short* vT = (unsigned short*)(ws + 16777216);      // 8 MiB
    unsigned short* Wt = (unsigned short*)(ws + 25165824);      // 144 KiB

    prep_wt<<<288, 256, 0, stream>>>(Wq, Wk, Wv, Wt);
    qkv_kernel<<<1024, 256, 0, stream>>>(x, Wt, q, kk, vT);
    attn_kernel<<<dim3(4, 256), 256, 0, stream>>>(q, kk, vT, relk, relv, out);
}

// Round 4
// 208.514 us; speedup vs baseline: 1.2516x; 1.2516x over previous
//
#include <hip/hip_runtime.h>
#include <hip/hip_bf16.h>

// Problem: B=256, T=256, C=384, H=64, MAX_REL=3 (causal -> rel idx 0..3 only)
// Round 4:
//   prep_wt: Wt[3][64][384] bf16 (transposed weights) + Rk[16][64] bf16 (rel_k rows)
//   qkv_kernel: round-1 proven LDS-staged projection (512 thr, 128 rows/block)
//   attn_kernel: ONE WAVE per block (grid 16x256, 64 thr). No cross-wave coupling,
//     no score residency (unnormalized exp -> LDS immediately), normalize folded
//     into output, E via MFMA vs Rk, band-prob w2 identity.

typedef __attribute__((ext_vector_type(8))) __bf16 bf16x8;
typedef __attribute__((ext_vector_type(8))) short short8;
typedef __attribute__((ext_vector_type(4))) float f32x4;
typedef __attribute__((ext_vector_type(4))) int   i32x4;

#define MFMA16(A, B, C) __builtin_amdgcn_mfma_f32_16x16x32_bf16((A), (B), (C), 0, 0, 0)

__device__ __forceinline__ unsigned short f2bf(float f) {
    unsigned int u = __builtin_bit_cast(unsigned int, f);
    u = (u + 0x7FFFu + ((u >> 16) & 1u)) >> 16;   // RNE
    return (unsigned short)u;
}
__device__ __forceinline__ float bf2f(unsigned short s) {
    unsigned int u = ((unsigned int)s) << 16;
    return __builtin_bit_cast(float, u);
}
__device__ __forceinline__ bf16x8 ld16(const unsigned short* p) {
    return __builtin_bit_cast(bf16x8, *(const i32x4*)p);
}

// ---------------------------------------------------------------------------
// Kernel 0: Wt[3][64][384] bf16 (W^T) + Rk[16][64] bf16 (rel_k rows 0..3, rest 0)
// ---------------------------------------------------------------------------
__global__ void prep_wt(const float* __restrict__ Wq, const float* __restrict__ Wk,
                        const float* __restrict__ Wv, const float* __restrict__ relk,
                        unsigned short* __restrict__ Wt, unsigned short* __restrict__ Rk) {
    int i = blockIdx.x * 256 + threadIdx.x;           // 73728 + 1024 jobs
    if (i < 3 * 64 * 384) {
        int kk = i % 384;
        int h  = (i / 384) & 63;
        int w  = i / (384 * 64);
        const float* W = (w == 0) ? Wq : ((w == 1) ? Wk : Wv);
        Wt[i] = f2bf(W[kk * 64 + h]);
    } else if (i < 3 * 64 * 384 + 1024) {
        int j = i - 3 * 64 * 384;                      // 0..1023
        int n = j >> 6, h = j & 63;
        Rk[j] = (n < 4) ? f2bf(relk[n * 64 + h]) : (unsigned short)0;
    }
}

// ---------------------------------------------------------------------------
// Kernel 1: fused QKV projection (round-1 proven).
//   512 thr (8 waves), 128 rows/block, grid 512. Wt staged via LDS in 3
//   k-chunks of 128 (rows padded to 136 -> b128 reads 2 lanes/bank = free).
//   v produced TRANSPOSED (vT[b][h][t]) by swapping MFMA operands.
// ---------------------------------------------------------------------------
__global__ __launch_bounds__(512) void qkv_kernel(
        const float* __restrict__ x, const unsigned short* __restrict__ Wt,
        unsigned short* __restrict__ q, unsigned short* __restrict__ k,
        unsigned short* __restrict__ vT) {
    __shared__ unsigned short wlds[192][136];          // 52224 B

    const int tid  = threadIdx.x;
    const int wave = tid >> 6;
    const int lane = tid & 63;
    const int c    = lane & 15;
    const int quad = lane >> 4;
    const int M0   = blockIdx.x * 128;
    const int myrow = M0 + wave * 16 + c;              // x row owned by this lane

    f32x4 zero = {0.f, 0.f, 0.f, 0.f};
    f32x4 aq[4], ak[4], av[4];
#pragma unroll
    for (int i = 0; i < 4; i++) { aq[i] = zero; ak[i] = zero; av[i] = zero; }

    for (int ck = 0; ck < 3; ck++) {
        if (ck) __syncthreads();                       // prev chunk reads done
#pragma unroll
        for (int it = 0; it < 6; it++) {
            int i = it * 512 + tid;                    // 192*16 = 3072 16B pieces
            int r = i >> 4, kc = i & 15;
            i32x4 d = *(const i32x4*)(Wt + r * 384 + ck * 128 + kc * 8);
            *(i32x4*)(&wlds[r][kc * 8]) = d;
        }
        __syncthreads();

#pragma unroll
        for (int ks = 0; ks < 4; ks++) {
            const float* xp = x + (size_t)myrow * 384 + ck * 128 + ks * 32 + quad * 8;
            f32x4 x0 = *(const f32x4*)xp;
            f32x4 x1 = *(const f32x4*)(xp + 4);
            short8 xs;
#pragma unroll
            for (int j = 0; j < 4; j++) {
                xs[j]     = (short)f2bf(x0[j]);
                xs[4 + j] = (short)f2bf(x1[j]);
            }
            bf16x8 a = __builtin_bit_cast(bf16x8, xs);

#pragma unroll
            for (int nt = 0; nt < 8; nt++) {           // q: nt 0..3, k: nt 4..7
                bf16x8 b = ld16(&wlds[nt * 16 + c][ks * 32 + quad * 8]);
                if (nt < 4) aq[nt]     = MFMA16(a, b, aq[nt]);
                else        ak[nt - 4] = MFMA16(a, b, ak[nt - 4]);
            }
#pragma unroll
            for (int mt = 0; mt < 4; mt++) {           // vT: A = Wv^T rows
                bf16x8 aw = ld16(&wlds[128 + mt * 16 + c][ks * 32 + quad * 8]);
                av[mt] = MFMA16(aw, a, av[mt]);
            }
        }
    }

    // epilogue: C/D layout col=lane&15, row=quad*4+reg
    const int b   = M0 >> 8;
    const int t0b = M0 & 255;
#pragma unroll
    for (int nt = 0; nt < 4; nt++) {
#pragma unroll
        for (int r = 0; r < 4; r++) {
            int row = M0 + wave * 16 + quad * 4 + r;
            q[row * 64 + nt * 16 + c] = f2bf(aq[nt][r]);
            k[row * 64 + nt * 16 + c] = f2bf(ak[nt][r]);
        }
    }
#pragma unroll
    for (int mt = 0; mt < 4; mt++) {
#pragma unroll
        for (int r = 0; r < 4; r++) {
            int h = mt * 16 + quad * 4 + r;
            vT[(b * 64 + h) * 256 + t0b + wave * 16 + c] = f2bf(av[mt][r]);
        }
    }
}

// ---------------------------------------------------------------------------
// Kernel 2: attention, ONE WAVE per block. Grid (16, 256): x = 16-row q-tile,
//   y = batch. Wave handles q rows [16tt, 16tt+16), s in [0, 16(tt+1)).
//   Unnormalized P^ = exp(score) -> wave-private LDS immediately (no max pass;
//   scores bounded ~|8|). Row sums l in regs; 1/l folded into output epilogue.
// ---------------------------------------------------------------------------
__global__ __launch_bounds__(64, 4) void attn_kernel(
        const unsigned short* __restrict__ q, const unsigned short* __restrict__ k,
        const unsigned short* __restrict__ vT, const unsigned short* __restrict__ Rk,
        const float* __restrict__ relv, float* __restrict__ out) {
    __shared__ unsigned short P[16][264];              // 8448 B (unnormalized P^)
    __shared__ float E[16][4];

    const int lane = threadIdx.x;
    const int c    = lane & 15;
    const int quad = lane >> 4;
    const int tt   = blockIdx.x;
    const int b    = blockIdx.y;
    const int t0   = tt * 16;
    const int nst  = tt + 1;                           // valid 16-wide s-tiles

    f32x4 zero = {0.f, 0.f, 0.f, 0.f};

    // relv preload (L2-hot, 16 coalesced f32 per lane)
    float rv[4][4];
#pragma unroll
    for (int j = 0; j < 4; j++)
#pragma unroll
        for (int nt = 0; nt < 4; nt++) rv[j][nt] = relv[j * 64 + nt * 16 + c];

    // q A-frags: lane's A-row m = c -> q row t0+c
    const unsigned short* qp = q + (size_t)(b * 256 + t0 + c) * 64 + quad * 8;
    bf16x8 aq0 = ld16(qp);
    bf16x8 aq1 = ld16(qp + 32);

    // E via MFMA vs Rk: D[m=quad*4+r][n=c] = q_{t0+m} . relk_n  (n<4 valid)
    {
        f32x4 e = zero;
        e = MFMA16(aq0, ld16(Rk + c * 64 + quad * 8), e);
        e = MFMA16(aq1, ld16(Rk + c * 64 + 32 + quad * 8), e);
        if (c < 4) {
#pragma unroll
            for (int r = 0; r < 4; r++) E[quad * 4 + r][c] = e[r];
        }
    }
    __syncthreads();                                   // single wave: cheap
    f32x4 ef[4];
#pragma unroll
    for (int r = 0; r < 4; r++) ef[r] = *(const f32x4*)(&E[quad * 4 + r][0]);

    // score tiles -> exp -> LDS; accumulate row sums
    float l[4] = {0.f, 0.f, 0.f, 0.f};
#pragma unroll
    for (int st = 0; st < 16; st++) {
        if (st < nst) {
            const unsigned short* kp = k + (size_t)(b * 256 + st * 16 + c) * 64 + quad * 8;
            f32x4 s = zero;
            s = MFMA16(aq0, ld16(kp), s);
            s = MFMA16(aq1, ld16(kp + 32), s);
#pragma unroll
            for (int r = 0; r < 4; r++) {
                int tg = t0 + quad * 4 + r;            // global q row
                int sg = st * 16 + c;                  // global s
                int d  = sg - tg;
                float e = (d <= -3) ? ef[r][0] : (d == -2) ? ef[r][1]
                        : (d == -1) ? ef[r][2] : ef[r][3];
                float p = (d > 0) ? 0.f : __expf(0.125f * (s[r] + e));
                l[r] += p;
                P[quad * 4 + r][sg] = f2bf(p);
            }
        }
    }
    // zero-pad the half-open MFMA k-tile when nst is odd
    if (nst & 1) {
#pragma unroll
        for (int r = 0; r < 4; r++) P[quad * 4 + r][nst * 16 + c] = 0;
    }
    // row-sum over the 16 c-lanes (same quad)
#pragma unroll
    for (int r = 0; r < 4; r++)
#pragma unroll
        for (int ofs = 1; ofs < 16; ofs <<= 1)
            l[r] += __shfl_xor(l[r], ofs, 64);
    float rl[4];
#pragma unroll
    for (int r = 0; r < 4; r++) rl[r] = 1.0f / l[r];
    __syncthreads();                                   // P^ visible (single wave)

    // O = P^ @ V  (A rows m=c from LDS; B = vT rows from global)
    f32x4 o[4];
#pragma unroll
    for (int nt = 0; nt < 4; nt++) o[nt] = zero;
    const int ksteps = (nst + 1) >> 1;
#pragma unroll
    for (int ks = 0; ks < 8; ks++) {
        if (ks < ksteps) {
            bf16x8 ap = ld16(&P[c][ks * 32 + quad * 8]);
#pragma unroll
            for (int nt = 0; nt < 4; nt++) {
                const unsigned short* vp = vT + (size_t)(b * 64 + nt * 16 + c) * 256
                                              + ks * 32 + quad * 8;
                o[nt] = MFMA16(ap, ld16(vp), o[nt]);
            }
        }
    }

    // epilogue: normalize + w2 band-probability identity + store
#pragma unroll
    for (int r = 0; r < 4; r++) {
        int tl = quad * 4 + r;
        int tg = t0 + tl;
        float pa = (tg >= 2) ? bf2f(P[tl][tg - 2]) * rl[r] : 0.f;
        float pb = (tg >= 1) ? bf2f(P[tl][tg - 1]) * rl[r] : 0.f;
        float pc = bf2f(P[tl][tg]) * rl[r];
#pragma unroll
        for (int nt = 0; nt < 4; nt++) {
            float r0 = rv[0][nt];
            float w2 = r0 + pa * (rv[1][nt] - r0) + pb * (rv[2][nt] - r0)
                          + pc * (rv[3][nt] - r0);
            out[(size_t)(b * 256 + tg) * 64 + nt * 16 + c] = o[nt][r] * rl[r] + w2;
        }
    }
}

// ---------------------------------------------------------------------------
extern "C" void kernel_launch(void* const* d_in, const int* in_sizes, int n_in,
                              void* d_out, int out_size, void* d_ws, size_t ws_size,
                              hipStream_t stream) {
    const float* x    = (const float*)d_in[0];
    const float* Wq   = (const float*)d_in[1];
    const float* Wk   = (const float*)d_in[2];
    const float* Wv   = (const float*)d_in[3];
    const float* relk = (const float*)d_in[4];
    const float* relv = (const float*)d_in[5];
    float* out = (float*)d_out;

    char* ws = (char*)d_ws;
    unsigned short* q  = (unsigned short*)(ws);                 // 8 MiB
    unsigned short* kk = (unsigned short*)(ws + 8388608);       // 8 MiB
    unsigned short* vT = (unsigned short*)(ws + 16777216);      // 8 MiB
    unsigned short* Wt = (unsigned short*)(ws + 25165824);      // 144 KiB
    unsigned short* Rk = (unsigned short*)(ws + 25313280);      // 2 KiB

    prep_wt<<<292, 256, 0, stream>>>(Wq, Wk, Wv, relk, Wt, Rk);
    qkv_kernel<<<512, 512, 0, stream>>>(x, Wt, q, kk, vT);
    attn_kernel<<<dim3(16, 256), 64, 0, stream>>>(q, kk, vT, Rk, relv, out);
}